// Round 11
// baseline (730.459 us; speedup 1.0000x reference)
//
#include <hip/hip_runtime.h>

// ConvLSTM B=4 T=16 C=1 H=W=64 HID=64, 2 layers, k=3 SAME.
// Round 6 design (5th resubmit; repeated infra timeouts): nt=4 (16x16 px
// tile, r=0.5 LDS reads/MFMA) + full double-buffer (sIn x2, sW x2 = 125KB
// LDS, 1 block/CU) + issue-early/write-late staging, ONE barrier per chunk.
// Block (256 thr, 4 waves) = 16x16 px x 16 hid x 4 gates.

typedef __attribute__((ext_vector_type(8))) short short8;
typedef __attribute__((ext_vector_type(4))) float float4v;
typedef unsigned short ushort_t;
typedef unsigned int uint_t;

#define HID 64
constexpr int PIX = 4096;
constexpr int HP = 72;                 // padded row stride (els)
constexpr int PROWS = 66;              // rows: y=-1..64
constexpr int PIMG = HP * PROWS;       // 4752 els per padded plane
constexpr int LDSW = 18;               // halo cols
constexpr int HROWS = 18;              // halo rows (16 + 2)
constexpr int HALO = HROWS * LDSW;     // 324
constexpr int SPAD = 40;               // sIn stride per pixel (els)
constexpr int WCHUNK = 18432;          // weight els per (hg, chunk)
constexpr int NJOBS = HROWS * 32;      // 576 staging jobs

__device__ __forceinline__ ushort_t f2b(float f) {
    uint_t u = __float_as_uint(f);
    return (ushort_t)((u + 0x7fffu + ((u >> 16) & 1u)) >> 16);  // RNE
}
__device__ __forceinline__ float sigm(float x) { return 1.f / (1.f + __expf(-x)); }
__device__ __forceinline__ float tanh_fast(float x) {
    float e = __expf(2.f * x);
    return 1.f - 2.f / (e + 1.f);
}
__device__ __forceinline__ void gl_lds16(const ushort_t* g, ushort_t* l) {
    __builtin_amdgcn_global_load_lds(
        (const __attribute__((address_space(1))) unsigned int*)g,
        (__attribute__((address_space(3))) unsigned int*)l, 16, 0, 0);
}

// x [4][16][64][64] f32 -> padded bf16 planes [b*16+t][66][72] (pre-zeroed)
__global__ void cvt_pad_x(const float* __restrict__ src, ushort_t* __restrict__ dst) {
    int i = blockIdx.x * 256 + threadIdx.x;  // 262144
    int bt = i >> 12, p = i & 4095, y = p >> 6, xx = p & 63;
    dst[bt * PIMG + (y + 1) * HP + xx + 1] = f2b(src[i]);
}

// Wp layout: [hg][ck][tap][cg][gate][hid16][8j]; channel c = ck*32+cg*8+j.
// L0: our channel order = [h(0..63), x, zeros]; w's order = [x, h(0..63)].
template <int CIN, int NCH, bool L0>
__global__ void pack_w(const float* __restrict__ w, ushort_t* __restrict__ Wp, int total) {
    int e = blockIdx.x * 256 + threadIdx.x;
    if (e >= total) return;
    int j = e & 7;
    int hidL = (e >> 3) & 15;
    int g = (e >> 7) & 3;
    int cg = (e >> 9) & 3;
    int r = e >> 11;
    int tap = r % 9; r /= 9;
    int ck = r % NCH;
    int hg = r / NCH;
    int c = ck * 32 + cg * 8 + j;
    int outc = g * 64 + hg * 16 + hidL;
    int wch;
    if (L0) wch = (c < 64) ? c + 1 : (c == 64 ? 0 : -1);
    else    wch = (c < CIN) ? c : -1;
    Wp[e] = (wch >= 0) ? f2b(w[(outc * CIN + wch) * 9 + tap]) : (ushort_t)0;
}

// ---- staging helpers (jobs: 576 = 18 halo rows x 32 ch) ----
template <int CINV>
__device__ __forceinline__ void stage_load(const ushort_t* __restrict__ srcA,
                                           const ushort_t* __restrict__ srcB,
                                           int bstrB, int ck, int b, int by, int bx,
                                           int tid, short8 (&V)[3][3]) {
#pragma unroll
    for (int jj = 0; jj < 3; ++jj) {
        int job = tid + jj * 256;
        if (job < NJOBS) {
            int hrow = job >> 5, ch = job & 31;
            int gch = ck * 32 + ch;
            const ushort_t* p = nullptr;
            if (gch < 64)
                p = srcA + (size_t)(b * 64 + gch) * PIMG;
            else if (gch < CINV)
                p = srcB + (size_t)b * bstrB + (size_t)(gch - 64) * PIMG;
            if (p) {
                p += (by + hrow) * HP + bx;  // padded row, col bx (8-aligned)
                V[jj][0] = *(const short8*)(p);
                V[jj][1] = *(const short8*)(p + 8);
                V[jj][2] = *(const short8*)(p + 16);
            } else {
                short8 z = {};
                V[jj][0] = z; V[jj][1] = z; V[jj][2] = z;
            }
        }
    }
}

__device__ __forceinline__ void stage_write(ushort_t* __restrict__ sIn, int tid,
                                            short8 (&V)[3][3]) {
#pragma unroll
    for (int jj = 0; jj < 3; ++jj) {
        int job = tid + jj * 256;
        if (job < NJOBS) {
            int hrow = job >> 5, ch = job & 31;
            ushort_t* dst = sIn + hrow * LDSW * SPAD + ch;
#pragma unroll
            for (int k = 0; k < 3; ++k)
#pragma unroll
                for (int ii = 0; ii < 8; ++ii) {
                    int hx = k * 8 + ii;
                    if (hx < LDSW) dst[hx * SPAD] = (ushort_t)V[jj][k][ii];
                }
        }
    }
}

template <int CINV, int NCH>
__global__ __launch_bounds__(256, 1) void cell_mfma(
    const ushort_t* __restrict__ srcA,  // padded, channels [0,64)
    const ushort_t* __restrict__ srcB,  // padded, channels [64,CINV)
    int bstrB,
    const ushort_t* __restrict__ Wp,
    const float* __restrict__ bias,
    float* __restrict__ cst,
    ushort_t* __restrict__ hnext,       // padded
    float* __restrict__ out)            // null, or d_out + t*HID*PIX
{
    __shared__ __align__(16) ushort_t sIn0[HALO * SPAD];  // 25920 B
    __shared__ __align__(16) ushort_t sIn1[HALO * SPAD];  // 25920 B
    __shared__ __align__(16) ushort_t sW0[WCHUNK];        // 36864 B
    __shared__ __align__(16) ushort_t sW1[WCHUNK];        // 36864 B

    const int tid = threadIdx.x;
    const int lane = tid & 63;
    const int wq = tid >> 6;
    const int x = lane & 15;
    const int q = lane >> 4;
    const int b = blockIdx.x >> 4;
    const int pt = blockIdx.x & 15;
    const int by = (pt >> 2) << 4, bx = (pt & 3) << 4;
    const int hg = blockIdx.y;

    float4v acc[4][4];
#pragma unroll
    for (int m = 0; m < 4; ++m) {
        float4v bv;
#pragma unroll
        for (int r = 0; r < 4; ++r) bv[r] = bias[m * 64 + hg * 16 + q * 4 + r];
#pragma unroll
        for (int nt = 0; nt < 4; ++nt) acc[m][nt] = bv;
    }

    const int abase = q * 512 + x * 8;
    int bb[4];
#pragma unroll
    for (int nt = 0; nt < 4; ++nt)
        bb[nt] = ((wq * 4 + nt) * LDSW + x) * SPAD + q * 8;

    const ushort_t* wbase = Wp + (size_t)hg * NCH * WCHUNK;

#define STAGE_W(ck, sw)                                                      \
    {                                                                        \
        const ushort_t* wsrc = wbase + (ck) * WCHUNK;                        \
        _Pragma("unroll") for (int k = 0; k < 9; ++k)                        \
            gl_lds16(wsrc + (k * 256 + tid) * 8, &(sw)[(k * 256 + tid) * 8]);\
    }

#define COMPUTE(si, sw)                                                      \
    {                                                                        \
        _Pragma("unroll") for (int tap = 0; tap < 9; ++tap) {                \
            const int dy = tap / 3, dxo = tap - dy * 3;                      \
            short8 a[4];                                                     \
            const ushort_t* wp_ = (sw) + tap * 2048 + abase;                 \
            _Pragma("unroll") for (int m = 0; m < 4; ++m)                    \
                a[m] = *(const short8*)(wp_ + m * 128);                      \
            _Pragma("unroll") for (int nt = 0; nt < 4; ++nt) {               \
                short8 bf = *(const short8*)&(si)[bb[nt] + (dy * LDSW + dxo) * SPAD]; \
                _Pragma("unroll") for (int m = 0; m < 4; ++m)                \
                    acc[m][nt] = __builtin_amdgcn_mfma_f32_16x16x32_bf16(    \
                        a[m], bf, acc[m][nt], 0, 0, 0);                      \
            }                                                                \
        }                                                                    \
    }

    short8 V[3][3];
    // prologue: chunk 0 staged with exposed latency (once)
    stage_load<CINV>(srcA, srcB, bstrB, 0, b, by, bx, tid, V);
    STAGE_W(0, sW0);
    stage_write(sIn0, tid, V);
    __syncthreads();

#pragma unroll
    for (int ck = 0; ck < NCH; ++ck) {
        ushort_t* sI  = (ck & 1) ? sIn1 : sIn0;
        ushort_t* sWc = (ck & 1) ? sW1 : sW0;
        ushort_t* sIa = (ck & 1) ? sIn0 : sIn1;
        ushort_t* sWa = (ck & 1) ? sW0 : sW1;
        if (ck + 1 < NCH) {
            // issue next chunk's global loads + weight DMA BEFORE compute
            stage_load<CINV>(srcA, srcB, bstrB, ck + 1, b, by, bx, tid, V);
            STAGE_W(ck + 1, sWa);
        }
        COMPUTE(sI, sWc);
        if (ck + 1 < NCH)
            stage_write(sIa, tid, V);  // loads landed during compute
        __syncthreads();
    }

    // fused LSTM epilogue: m = gate (i,f,o,g)
#pragma unroll
    for (int nt = 0; nt < 4; ++nt) {
        int iy = by + wq * 4 + nt, ix = bx + x;
        int px = iy * 64 + ix;
#pragma unroll
        for (int r = 0; r < 4; ++r) {
            int hid = hg * 16 + q * 4 + r;
            int idx = (b * HID + hid) * PIX + px;
            float ig = sigm(acc[0][nt][r]);
            float fg = sigm(acc[1][nt][r]);
            float og = sigm(acc[2][nt][r]);
            float gg = tanh_fast(acc[3][nt][r]);
            float c = fg * cst[idx] + ig * gg;
            float h = og * tanh_fast(c);
            cst[idx] = c;
            hnext[(size_t)(b * HID + hid) * PIMG + (iy + 1) * HP + ix + 1] = f2b(h);
            if (out) out[(size_t)b * (16 * HID * PIX) + (size_t)hid * PIX + px] = h;
        }
    }
#undef STAGE_W
#undef COMPUTE
}

extern "C" void kernel_launch(void* const* d_in, const int* in_sizes, int n_in,
                              void* d_out, int out_size, void* d_ws, size_t ws_size,
                              hipStream_t stream) {
    const float* xf = (const float*)d_in[0];  // [4][16][1][64][64]
    const float* w0 = (const float*)d_in[1];  // [256][65][3][3]
    const float* b0 = (const float*)d_in[2];
    const float* w1 = (const float*)d_in[3];  // [256][128][3][3]
    const float* b1 = (const float*)d_in[4];
    float* out = (float*)d_out;               // [4][16][64][64][64]

    char* ws = (char*)d_ws;
    const size_t HBUF = (size_t)4 * HID * PIMG;       // 1,216,512 els
    ushort_t* h0a = (ushort_t*)ws;
    ushort_t* h0b = h0a + HBUF;
    ushort_t* h1a = h0b + HBUF;
    ushort_t* h1b = h1a + HBUF;
    ushort_t* xpad = h1b + HBUF;                      // 4*16*PIMG = 304,128 els
    float* c0 = (float*)(xpad + (size_t)4 * 16 * PIMG);
    float* c1 = c0 + (size_t)4 * HID * PIX;           // 1,048,576 f32 each
    ushort_t* Wp0 = (ushort_t*)(c1 + (size_t)4 * HID * PIX);  // 221,184 els
    ushort_t* Wp1 = Wp0 + 221184;                             // 294,912 els

    // zero h(x4, padded) + xpad + c0 + c1 : one contiguous region
    size_t zbytes = (4 * HBUF + (size_t)4 * 16 * PIMG) * sizeof(ushort_t) +
                    (size_t)2 * 4 * HID * PIX * sizeof(float);
    hipMemsetAsync(d_ws, 0, zbytes, stream);

    cvt_pad_x<<<262144 / 256, 256, 0, stream>>>(xf, xpad);
    pack_w<65, 3, true><<<221184 / 256, 256, 0, stream>>>(w0, Wp0, 221184);
    pack_w<128, 4, false><<<294912 / 256, 256, 0, stream>>>(w1, Wp1, 294912);

    dim3 grid(64, 4), blk(256);  // 256 blocks = 1/CU (125KB LDS forces this too)
    for (int t = 0; t < 16; ++t) {
        ushort_t* h0r = (t & 1) ? h0b : h0a;
        ushort_t* h0w = (t & 1) ? h0a : h0b;
        ushort_t* h1r = (t & 1) ? h1b : h1a;
        ushort_t* h1w = (t & 1) ? h1a : h1b;
        // layer0: channels [h0(64), x(1)] ; srcB = x plane for (b,t)
        cell_mfma<65, 3><<<grid, blk, 0, stream>>>(
            h0r, xpad + (size_t)t * PIMG, 16 * PIMG, Wp0, b0, c0, h0w, nullptr);
        // layer1: channels [h0(64), h1(64)]
        cell_mfma<128, 4><<<grid, blk, 0, stream>>>(
            h0w, h1r, HID * PIMG, Wp1, b1, c1, h1w,
            out + (size_t)t * HID * PIX);
    }
}

// Round 13
// 684.414 us; speedup vs baseline: 1.0673x; 1.0673x over previous
//
#include <hip/hip_runtime.h>

// ConvLSTM B=4 T=16 C=1 H=W=64 HID=64, 2 layers, k=3 SAME.
// Round 12 (resubmit; infra timeout): occupancy attack. hid-group 16 -> 8:
// grid(64,8)=512 blocks, LDS 44KB -> 3 blocks/CU (12 waves/CU vs 4).
// Wave = 16x16 px x 8 hid x 4 gates (2 A-frags, 4 B-frags, 8 MFMA/tap).
// A-frag row = (hid&3)*4+gate so each thread holds all 4 gates of its hid
// channels (fused epilogue). Round-4 skeleton: reg ping-pong, single buffers.

typedef __attribute__((ext_vector_type(8))) short short8;
typedef __attribute__((ext_vector_type(4))) float float4v;
typedef unsigned short ushort_t;
typedef unsigned int uint_t;

#define HID 64
constexpr int PIX = 4096;
constexpr int HP = 72;                 // padded row stride (els)
constexpr int PROWS = 66;              // rows: y=-1..64
constexpr int PIMG = HP * PROWS;       // 4752 els per padded plane
constexpr int LDSW = 18;               // halo cols
constexpr int HROWS = 18;              // halo rows (16 + 2)
constexpr int HALO = HROWS * LDSW;     // 324
constexpr int SPAD = 40;               // sIn stride per pixel (els)
constexpr int WCHUNK = 9216;           // weight els per (hg, chunk)
constexpr int W16 = WCHUNK / 8;        // 1152 16B units
constexpr int NJOBS = HROWS * 32;      // 576 staging jobs

__device__ __forceinline__ ushort_t f2b(float f) {
    uint_t u = __float_as_uint(f);
    return (ushort_t)((u + 0x7fffu + ((u >> 16) & 1u)) >> 16);  // RNE
}
__device__ __forceinline__ float sigm(float x) { return 1.f / (1.f + __expf(-x)); }
__device__ __forceinline__ float tanh_fast(float x) {
    float e = __expf(2.f * x);
    return 1.f - 2.f / (e + 1.f);
}
__device__ __forceinline__ void gl_lds16(const ushort_t* g, ushort_t* l) {
    __builtin_amdgcn_global_load_lds(
        (const __attribute__((address_space(1))) unsigned int*)g,
        (__attribute__((address_space(3))) unsigned int*)l, 16, 0, 0);
}

// x [4][16][64][64] f32 -> padded bf16 planes [b*16+t][66][72] (pre-zeroed)
__global__ void cvt_pad_x(const float* __restrict__ src, ushort_t* __restrict__ dst) {
    int i = blockIdx.x * 256 + threadIdx.x;  // 262144
    int bt = i >> 12, p = i & 4095, y = p >> 6, xx = p & 63;
    dst[bt * PIMG + (y + 1) * HP + xx + 1] = f2b(src[i]);
}

// Wp layout: [hg(8)][ck][tap][cg(4)][mf(2)][row16][j8];
// row = hq*4 + gate (hq = hid&3), outc = gate*64 + hg*8 + mf*4 + hq,
// channel c = ck*32 + cg*8 + j.
// L0: our channel order = [h(0..63), x, zeros]; w's order = [x, h(0..63)].
template <int CIN, int NCH, bool L0>
__global__ void pack_w(const float* __restrict__ w, ushort_t* __restrict__ Wp, int total) {
    int e = blockIdx.x * 256 + threadIdx.x;
    if (e >= total) return;
    int j = e & 7;
    int row = (e >> 3) & 15;
    int mf = (e >> 7) & 1;
    int cg = (e >> 8) & 3;
    int r2 = e >> 10;
    int tap = r2 % 9; r2 /= 9;
    int ck = r2 % NCH;
    int hg = r2 / NCH;
    int hq = row >> 2, g = row & 3;
    int outc = g * 64 + hg * 8 + mf * 4 + hq;
    int c = ck * 32 + cg * 8 + j;
    int wch;
    if (L0) wch = (c < 64) ? c + 1 : (c == 64 ? 0 : -1);
    else    wch = (c < CIN) ? c : -1;
    Wp[e] = (wch >= 0) ? f2b(w[(outc * CIN + wch) * 9 + tap]) : (ushort_t)0;
}

// ---- staging helpers (jobs: 576 = 18 halo rows x 32 ch) ----
template <int CINV>
__device__ __forceinline__ void stage_load(const ushort_t* __restrict__ srcA,
                                           const ushort_t* __restrict__ srcB,
                                           int bstrB, int ck, int b, int by, int bx,
                                           int tid, short8 (&V)[3][3]) {
#pragma unroll
    for (int jj = 0; jj < 3; ++jj) {
        int job = tid + jj * 256;
        if (job < NJOBS) {
            int hrow = job >> 5, ch = job & 31;
            int gch = ck * 32 + ch;
            const ushort_t* p = nullptr;
            if (gch < 64)
                p = srcA + (size_t)(b * 64 + gch) * PIMG;
            else if (gch < CINV)
                p = srcB + (size_t)b * bstrB + (size_t)(gch - 64) * PIMG;
            if (p) {
                p += (by + hrow) * HP + bx;  // padded row, col bx (8-aligned)
                V[jj][0] = *(const short8*)(p);
                V[jj][1] = *(const short8*)(p + 8);
                V[jj][2] = *(const short8*)(p + 16);
            } else {
                short8 z = {};
                V[jj][0] = z; V[jj][1] = z; V[jj][2] = z;
            }
        }
    }
}

__device__ __forceinline__ void stage_write(ushort_t* __restrict__ sIn, int tid,
                                            short8 (&V)[3][3]) {
#pragma unroll
    for (int jj = 0; jj < 3; ++jj) {
        int job = tid + jj * 256;
        if (job < NJOBS) {
            int hrow = job >> 5, ch = job & 31;
            ushort_t* dst = sIn + hrow * LDSW * SPAD + ch;
#pragma unroll
            for (int k = 0; k < 3; ++k)
#pragma unroll
                for (int ii = 0; ii < 8; ++ii) {
                    int hx = k * 8 + ii;
                    if (hx < LDSW) dst[hx * SPAD] = (ushort_t)V[jj][k][ii];
                }
        }
    }
}

template <int CINV, int NCH>
__global__ __launch_bounds__(256, 3) void cell_mfma(
    const ushort_t* __restrict__ srcA,  // padded, channels [0,64)
    const ushort_t* __restrict__ srcB,  // padded, channels [64,CINV)
    int bstrB,
    const ushort_t* __restrict__ Wp,
    const float* __restrict__ bias,
    float* __restrict__ cst,
    ushort_t* __restrict__ hnext,       // padded
    float* __restrict__ out)            // null, or d_out + t*HID*PIX
{
    __shared__ __align__(16) ushort_t sIn[HALO * SPAD];  // 25920 B
    __shared__ __align__(16) ushort_t sW[WCHUNK];        // 18432 B

    const int tid = threadIdx.x;
    const int lane = tid & 63;
    const int wq = tid >> 6;      // wave = 4 pixel rows
    const int x = lane & 15;
    const int q = lane >> 4;
    const int b = blockIdx.x >> 4;
    const int pt = blockIdx.x & 15;
    const int by = (pt >> 2) << 4, bx = (pt & 3) << 4;
    const int hg = blockIdx.y;    // hid group (8 ch)

    // acc[mf][nt]: mf = hid-quad frag, nt = pixel row; reg r = gate.
    // thread holds hid = hg*8 + mf*4 + q, gates 0..3.
    float4v acc[2][4];
#pragma unroll
    for (int mf = 0; mf < 2; ++mf) {
        float4v bv;
#pragma unroll
        for (int r = 0; r < 4; ++r) bv[r] = bias[r * 64 + hg * 8 + mf * 4 + q];
#pragma unroll
        for (int nt = 0; nt < 4; ++nt) acc[mf][nt] = bv;
    }

    const int abase = q * 256 + x * 8;  // cg=q chunk (256 els per cg)
    int bb[4];
#pragma unroll
    for (int nt = 0; nt < 4; ++nt)
        bb[nt] = ((wq * 4 + nt) * LDSW + x) * SPAD + q * 8;

    const ushort_t* wbase = Wp + (size_t)hg * NCH * WCHUNK;

#define STAGE_W(ck)                                                          \
    {                                                                        \
        const ushort_t* wsrc = wbase + (ck) * WCHUNK;                        \
        _Pragma("unroll") for (int k = 0; k < 5; ++k) {                      \
            int i_ = k * 256 + tid;                                          \
            if (i_ < W16) gl_lds16(wsrc + i_ * 8, &sW[i_ * 8]);              \
        }                                                                    \
    }

#define COMPUTE()                                                            \
    {                                                                        \
        _Pragma("unroll") for (int tap = 0; tap < 9; ++tap) {                \
            const int dy = tap / 3, dxo = tap - dy * 3;                      \
            short8 a[2];                                                     \
            const ushort_t* wp_ = sW + tap * 1024 + abase;                   \
            a[0] = *(const short8*)(wp_);                                    \
            a[1] = *(const short8*)(wp_ + 128);                              \
            _Pragma("unroll") for (int nt = 0; nt < 4; ++nt) {               \
                short8 bf = *(const short8*)&sIn[bb[nt] + (dy * LDSW + dxo) * SPAD]; \
                acc[0][nt] = __builtin_amdgcn_mfma_f32_16x16x32_bf16(        \
                    a[0], bf, acc[0][nt], 0, 0, 0);                          \
                acc[1][nt] = __builtin_amdgcn_mfma_f32_16x16x32_bf16(        \
                    a[1], bf, acc[1][nt], 0, 0, 0);                          \
            }                                                                \
        }                                                                    \
    }

    short8 VA[3][3], VB[3][3];
    stage_load<CINV>(srcA, srcB, bstrB, 0, b, by, bx, tid, VA);
#pragma unroll
    for (int ck = 0; ck < NCH; ck += 2) {
        __syncthreads();
        if (ck + 1 < NCH)
            stage_load<CINV>(srcA, srcB, bstrB, ck + 1, b, by, bx, tid, VB);
        stage_write(sIn, tid, VA);
        STAGE_W(ck);
        __syncthreads();
        COMPUTE();
        if (ck + 1 < NCH) {
            __syncthreads();
            if (ck + 2 < NCH)
                stage_load<CINV>(srcA, srcB, bstrB, ck + 2, b, by, bx, tid, VA);
            stage_write(sIn, tid, VB);
            STAGE_W(ck + 1);
            __syncthreads();
            COMPUTE();
        }
    }

    // fused LSTM epilogue: reg r = gate (i,f,o,g); hid = hg*8 + mf*4 + q
#pragma unroll
    for (int nt = 0; nt < 4; ++nt) {
        int iy = by + wq * 4 + nt, ix = bx + x;
        int px = iy * 64 + ix;
#pragma unroll
        for (int mf = 0; mf < 2; ++mf) {
            int hid = hg * 8 + mf * 4 + q;
            int idx = (b * HID + hid) * PIX + px;
            float ig = sigm(acc[mf][nt][0]);
            float fg = sigm(acc[mf][nt][1]);
            float og = sigm(acc[mf][nt][2]);
            float gg = tanh_fast(acc[mf][nt][3]);
            float c = fg * cst[idx] + ig * gg;
            float h = og * tanh_fast(c);
            cst[idx] = c;
            hnext[(size_t)(b * HID + hid) * PIMG + (iy + 1) * HP + ix + 1] = f2b(h);
            if (out) out[(size_t)b * (16 * HID * PIX) + (size_t)hid * PIX + px] = h;
        }
    }
#undef STAGE_W
#undef COMPUTE
}

extern "C" void kernel_launch(void* const* d_in, const int* in_sizes, int n_in,
                              void* d_out, int out_size, void* d_ws, size_t ws_size,
                              hipStream_t stream) {
    const float* xf = (const float*)d_in[0];  // [4][16][1][64][64]
    const float* w0 = (const float*)d_in[1];  // [256][65][3][3]
    const float* b0 = (const float*)d_in[2];
    const float* w1 = (const float*)d_in[3];  // [256][128][3][3]
    const float* b1 = (const float*)d_in[4];
    float* out = (float*)d_out;               // [4][16][64][64][64]

    char* ws = (char*)d_ws;
    const size_t HBUF = (size_t)4 * HID * PIMG;       // 1,216,512 els
    ushort_t* h0a = (ushort_t*)ws;
    ushort_t* h0b = h0a + HBUF;
    ushort_t* h1a = h0b + HBUF;
    ushort_t* h1b = h1a + HBUF;
    ushort_t* xpad = h1b + HBUF;                      // 4*16*PIMG = 304,128 els
    float* c0 = (float*)(xpad + (size_t)4 * 16 * PIMG);
    float* c1 = c0 + (size_t)4 * HID * PIX;           // 1,048,576 f32 each
    ushort_t* Wp0 = (ushort_t*)(c1 + (size_t)4 * HID * PIX);  // 221,184 els
    ushort_t* Wp1 = Wp0 + 221184;                             // 294,912 els

    // zero h(x4, padded) + xpad + c0 + c1 : one contiguous region
    size_t zbytes = (4 * HBUF + (size_t)4 * 16 * PIMG) * sizeof(ushort_t) +
                    (size_t)2 * 4 * HID * PIX * sizeof(float);
    hipMemsetAsync(d_ws, 0, zbytes, stream);

    cvt_pad_x<<<262144 / 256, 256, 0, stream>>>(xf, xpad);
    pack_w<65, 3, true><<<221184 / 256, 256, 0, stream>>>(w0, Wp0, 221184);
    pack_w<128, 4, false><<<294912 / 256, 256, 0, stream>>>(w1, Wp1, 294912);

    dim3 grid(64, 8), blk(256);  // 512 blocks, 44KB LDS -> 3 blocks/CU
    for (int t = 0; t < 16; ++t) {
        ushort_t* h0r = (t & 1) ? h0b : h0a;
        ushort_t* h0w = (t & 1) ? h0a : h0b;
        ushort_t* h1r = (t & 1) ? h1b : h1a;
        ushort_t* h1w = (t & 1) ? h1a : h1b;
        // layer0: channels [h0(64), x(1)] ; srcB = x plane for (b,t)
        cell_mfma<65, 3><<<grid, blk, 0, stream>>>(
            h0r, xpad + (size_t)t * PIMG, 16 * PIMG, Wp0, b0, c0, h0w, nullptr);
        // layer1: channels [h0(64), h1(64)]
        cell_mfma<128, 4><<<grid, blk, 0, stream>>>(
            h0w, h1r, HID * PIMG, Wp1, b1, c1, h1w,
            out + (size_t)t * HID * PIX);
    }
}